// Round 11
// baseline (410.443 us; speedup 1.0000x reference)
//
#include <hip/hip_runtime.h>
#include <hip/hip_cooperative_groups.h>
#include <math.h>

namespace cg = cooperative_groups;

// Problem constants
constexpr int NB = 2;        // batch
constexpr int LQ = 2048;     // sequence length
constexpr int DD = 512;      // model dim
constexpr int PPL = 16;      // planes per set
constexpr int TPP = 64;      // total planes (S*P)
constexpr int FF = 128;      // feature dim = 2*TPP (cos,sin interleaved)
constexpr int NC = 32;       // chunks
constexpr int TC = 64;       // chunk length
constexpr int NCU = 256;     // MI355X CUs
constexpr float PI_F = 3.14159265358979323846f;

typedef __attribute__((ext_vector_type(4))) float f32x4;
typedef __attribute__((ext_vector_type(8))) short bf16x8;

static __device__ __forceinline__ unsigned short f2bf(float x) {
    union { float f; unsigned u; } v; v.f = x;
    unsigned r = v.u + 0x7fff + ((v.u >> 16) & 1);
    return (unsigned short)(r >> 16);
}
static __device__ __forceinline__ float bf2f(unsigned short u) {
    union { unsigned u; float f; } v; v.u = ((unsigned)u) << 16;
    return v.f;
}

// One kernel, 8 phases, 7 grid syncs. Grid-size-agnostic (all phases grid-stride).
// LDS: (128+64)*72 shorts = 27648 B (max over phases).
__global__ __launch_bounds__(256, 2) void mega_kernel(
    const float* __restrict__ x, const float* __restrict__ sw,
    const float* __restrict__ kw1, const float* __restrict__ kb1,
    const float* __restrict__ kw2, const float* __restrict__ kb2,
    const float* __restrict__ qw1, const float* __restrict__ qb1,
    const float* __restrict__ qw2, const float* __restrict__ qb2,
    const float* __restrict__ vw, const float* __restrict__ vb,
    const float* __restrict__ lng, const float* __restrict__ lnb,
    const float* __restrict__ ow, const float* __restrict__ ob,
    float* __restrict__ out, void* wsbase)
{
    cg::grid_group grid = cg::this_grid();
    __shared__ unsigned short smem[(128 + 64) * 72];
    const int tid = threadIdx.x;
    const int nb = gridDim.x;
    const size_t MR = (size_t)NB * LQ;  // 4096

    float* Rb = (float*)wsbase;
    unsigned short* xb   = (unsigned short*)(Rb + MR * DD);
    unsigned short* hkb  = xb + MR * DD;
    unsigned short* hqb  = hkb + MR * DD;
    unsigned short* YNb  = hqb + MR * DD;
    unsigned short* Vt   = YNb + MR * DD;
    unsigned short* CQb  = Vt + MR * DD;
    unsigned short* CKb  = CQb + MR * FF;
    unsigned short* CKt  = CKb + MR * FF;
    unsigned short* Stp  = CKt + MR * FF;
    unsigned short* Stb  = Stp + (size_t)NB * NC * DD * FF;
    unsigned short* kw1t = Stb + (size_t)NB * NC * DD * FF;
    unsigned short* qw1t = kw1t + (size_t)DD * DD;
    unsigned short* vwt  = qw1t + (size_t)DD * DD;
    unsigned short* owt  = vwt + (size_t)DD * DD;
    unsigned short* kw2t = owt + (size_t)DD * DD;
    unsigned short* qw2t = kw2t + (size_t)TPP * DD;

    const int w = tid >> 6, lane = tid & 63, grp = lane >> 4, lid = lane & 15;

    // ---------------- P0: cast x->bf16 (tiles 0..1023) + weight transposes (1024..2111) ----------------
    for (int t = blockIdx.x; t < 2112; t += nb) {
        if (t < 1024) {
            const int i = t * 2048 + tid * 8;
            float4 a = *(const float4*)(x + i);
            float4 b = *(const float4*)(x + i + 4);
            ushort4 u0 = {f2bf(a.x), f2bf(a.y), f2bf(a.z), f2bf(a.w)};
            ushort4 u1 = {f2bf(b.x), f2bf(b.y), f2bf(b.z), f2bf(b.w)};
            *(ushort4*)(xb + i) = u0;
            *(ushort4*)(xb + i + 4) = u1;
        } else {
            float* tf = (float*)smem;  // [32][33]
            const int id = t - 1024;
            const float* W;
            unsigned short* O;
            int K, N, n0, k0;
            if (id < 1024) {
                const int mat = id >> 8, rem = id & 255;
                W = (mat == 0) ? kw1 : (mat == 1) ? qw1 : (mat == 2) ? vw : ow;
                O = (mat == 0) ? kw1t : (mat == 1) ? qw1t : (mat == 2) ? vwt : owt;
                K = DD; N = DD;
                n0 = (rem & 15) * 32; k0 = (rem >> 4) * 32;
            } else {
                const int rid = id - 1024;
                const int mat = rid >> 5, rem = rid & 31;
                W = mat ? qw2 : kw2;
                O = mat ? qw2t : kw2t;
                K = DD; N = TPP;
                n0 = (rem & 1) * 32; k0 = (rem >> 1) * 32;
            }
            const int tx = tid & 31, ty = tid >> 5;  // 32x8
            __syncthreads();
#pragma unroll
            for (int i = 0; i < 4; ++i)
                tf[(ty + 8 * i) * 33 + tx] = W[(size_t)(k0 + ty + 8 * i) * N + n0 + tx];
            __syncthreads();
#pragma unroll
            for (int i = 0; i < 4; ++i)
                O[(size_t)(n0 + ty + 8 * i) * K + k0 + tx] = f2bf(tf[tx * 33 + ty + 8 * i]);
        }
    }
    grid.sync();

    // ---------------- P1: x-GEMMs (BM=128,BN=64): z=0 gelu->hkb, z=1 gelu->hqb, z=2 ->Vt ----------------
    for (int t = blockIdx.x; t < 768; t += nb) {
        const int cx = t & 7, ry = (t >> 3) & 31, z = t >> 8;
        const unsigned short* Bt = (z == 0) ? kw1t : (z == 1) ? qw1t : vwt;
        const float* bias = (z == 0) ? kb1 : (z == 1) ? qb1 : vb;
        unsigned short* obf = (z == 0) ? hkb : hqb;
        unsigned short* As = smem;             // 128*72
        unsigned short* Bs = smem + 128 * 72;  // 64*72
        const int wr = w >> 1, wc = w & 1;     // wave tile 64x32
        const int row0 = ry * 128, col0 = cx * 64;
        f32x4 acc[4][2];
#pragma unroll
        for (int m = 0; m < 4; ++m)
#pragma unroll
            for (int n = 0; n < 2; ++n) acc[m][n] = (f32x4)0.f;
        for (int k0 = 0; k0 < DD; k0 += 64) {
            bf16x8 va[4], vbv[2];
#pragma unroll
            for (int i = 0; i < 4; ++i) {
                const int c = tid + i * 256;
                va[i] = *(const bf16x8*)(xb + (size_t)(row0 + (c >> 3)) * DD + k0 + (c & 7) * 8);
            }
#pragma unroll
            for (int i = 0; i < 2; ++i) {
                const int c = tid + i * 256;
                vbv[i] = *(const bf16x8*)(Bt + (size_t)(col0 + (c >> 3)) * DD + k0 + (c & 7) * 8);
            }
            __syncthreads();
#pragma unroll
            for (int i = 0; i < 4; ++i) {
                const int c = tid + i * 256;
                *(bf16x8*)(As + (c >> 3) * 72 + (c & 7) * 8) = va[i];
            }
#pragma unroll
            for (int i = 0; i < 2; ++i) {
                const int c = tid + i * 256;
                *(bf16x8*)(Bs + (c >> 3) * 72 + (c & 7) * 8) = vbv[i];
            }
            __syncthreads();
#pragma unroll
            for (int kk = 0; kk < 2; ++kk) {
                bf16x8 af[4], bfr[2];
#pragma unroll
                for (int m = 0; m < 4; ++m)
                    af[m] = *(const bf16x8*)(As + (wr * 64 + m * 16 + lid) * 72 + kk * 32 + grp * 8);
#pragma unroll
                for (int n = 0; n < 2; ++n)
                    bfr[n] = *(const bf16x8*)(Bs + (wc * 32 + n * 16 + lid) * 72 + kk * 32 + grp * 8);
#pragma unroll
                for (int m = 0; m < 4; ++m)
#pragma unroll
                    for (int n = 0; n < 2; ++n)
                        acc[m][n] = __builtin_amdgcn_mfma_f32_16x16x32_bf16(af[m], bfr[n], acc[m][n], 0, 0, 0);
            }
        }
#pragma unroll
        for (int m = 0; m < 4; ++m) {
#pragma unroll
            for (int n = 0; n < 2; ++n) {
                const int col = col0 + wc * 32 + n * 16 + lid;
                const float bc = bias[col];
                if (z == 2) {
                    const int rowb = row0 + wr * 64 + m * 16 + grp * 4;
                    const int b = rowb >> 11, l = rowb & (LQ - 1);
                    const int c = l >> 6, t0 = l & 63;
                    ushort4 u;
                    u.x = f2bf(acc[m][n][0] + bc);
                    u.y = f2bf(acc[m][n][1] + bc);
                    u.z = f2bf(acc[m][n][2] + bc);
                    u.w = f2bf(acc[m][n][3] + bc);
                    *(ushort4*)(Vt + ((size_t)((b * NC + c) * DD) + col) * TC + t0) = u;
                } else {
#pragma unroll
                    for (int r = 0; r < 4; ++r) {
                        const int row = row0 + wr * 64 + m * 16 + grp * 4 + r;
                        float v = acc[m][n][r] + bc;
                        v = 0.5f * v * (1.0f + erff(v * 0.70710678118654752f));
                        obf[(size_t)row * DD + col] = f2bf(v);
                    }
                }
            }
        }
    }
    grid.sync();

    // ---------------- P2: phase GEMMs (BM=64, N=64, K=512); t>>6: 0=K,1=Q ----------------
    for (int t = blockIdx.x; t < 128; t += nb) {
        const int isq = t >> 6;
        const int row0 = (t & 63) * 64;
        const unsigned short* A = isq ? hqb : hkb;
        const unsigned short* Bt = isq ? qw2t : kw2t;
        const float* b2 = isq ? qb2 : kb2;
        unsigned short* FROW = isq ? CQb : CKb;
        unsigned short* As = smem;            // 64*72
        unsigned short* Bs = smem + 64 * 72;  // 64*72
        f32x4 acc[4];
#pragma unroll
        for (int n = 0; n < 4; ++n) acc[n] = (f32x4)0.f;
        for (int k0 = 0; k0 < DD; k0 += 64) {
            bf16x8 va[2], vbv[2];
#pragma unroll
            for (int i = 0; i < 2; ++i) {
                const int c = tid + i * 256;
                va[i] = *(const bf16x8*)(A + (size_t)(row0 + (c >> 3)) * DD + k0 + (c & 7) * 8);
                vbv[i] = *(const bf16x8*)(Bt + (size_t)(c >> 3) * DD + k0 + (c & 7) * 8);
            }
            __syncthreads();
#pragma unroll
            for (int i = 0; i < 2; ++i) {
                const int c = tid + i * 256;
                *(bf16x8*)(As + (c >> 3) * 72 + (c & 7) * 8) = va[i];
                *(bf16x8*)(Bs + (c >> 3) * 72 + (c & 7) * 8) = vbv[i];
            }
            __syncthreads();
#pragma unroll
            for (int kk = 0; kk < 2; ++kk) {
                bf16x8 af = *(const bf16x8*)(As + (w * 16 + lid) * 72 + kk * 32 + grp * 8);
                bf16x8 bfr[4];
#pragma unroll
                for (int n = 0; n < 4; ++n)
                    bfr[n] = *(const bf16x8*)(Bs + (n * 16 + lid) * 72 + kk * 32 + grp * 8);
#pragma unroll
                for (int n = 0; n < 4; ++n)
                    acc[n] = __builtin_amdgcn_mfma_f32_16x16x32_bf16(af, bfr[n], acc[n], 0, 0, 0);
            }
        }
        float wsm[4] = {1.f, 1.f, 1.f, 1.f};
        if (isq) {
            float s0 = sw[0], s1 = sw[1], s2 = sw[2], s3 = sw[3];
            float mx = fmaxf(fmaxf(s0, s1), fmaxf(s2, s3));
            float e0 = __expf(s0 - mx), e1 = __expf(s1 - mx), e2 = __expf(s2 - mx), e3 = __expf(s3 - mx);
            float inv = 1.0f / (e0 + e1 + e2 + e3);
            wsm[0] = e0 * inv; wsm[1] = e1 * inv; wsm[2] = e2 * inv; wsm[3] = e3 * inv;
        }
#pragma unroll
        for (int n = 0; n < 4; ++n) {
            const int p = n * 16 + lid;
            const float bc = b2[p];
            const float wg = isq ? wsm[p >> 4] : 1.0f;
#pragma unroll
            for (int r = 0; r < 4; ++r) {
                const int row = row0 + w * 16 + grp * 4 + r;
                float u = acc[n][r] + bc;
                float th = 1.0f - 2.0f / (__expf(2.0f * u) + 1.0f);   // tanh(u)
                float ph = th * PI_F;
                float sp, cp;
                __sincosf(ph, &sp, &cp);
                const unsigned short cb = f2bf(cp * wg), sb = f2bf(sp * wg);
                FROW[(size_t)row * FF + 2 * p + 0] = cb;
                FROW[(size_t)row * FF + 2 * p + 1] = sb;
                if (!isq) {
                    const int b = row >> 11, l = row & (LQ - 1);
                    const int c = l >> 6, tt = l & 63;
                    const size_t base = ((size_t)(b * NC + c) * FF) * TC;
                    CKt[base + (size_t)(2 * p + 0) * TC + tt] = cb;
                    CKt[base + (size_t)(2 * p + 1) * TC + tt] = sb;
                }
            }
        }
    }
    grid.sync();

    // ---------------- P3: passA — Stp[b][c][d][f] = sum_t Vt[d][t]*CKt[f][t], 512 tiles ----------------
    for (int t = blockIdx.x; t < 512; t += nb) {
        const int dq = t & 7, c = (t >> 3) & 31, b = t >> 8;
        const size_t cb = (size_t)(b * NC + c);
        const int d0 = dq * 64 + (w >> 1) * 32;
        const int f0 = (w & 1) * 64;
        f32x4 acc[2][4];
#pragma unroll
        for (int md = 0; md < 2; ++md)
#pragma unroll
            for (int nf = 0; nf < 4; ++nf) acc[md][nf] = (f32x4)0.f;
#pragma unroll
        for (int kt = 0; kt < 2; ++kt) {
            bf16x8 av[2], bk[4];
#pragma unroll
            for (int md = 0; md < 2; ++md)
                av[md] = *(const bf16x8*)(Vt + (cb * DD + d0 + md * 16 + lid) * TC + kt * 32 + grp * 8);
#pragma unroll
            for (int nf = 0; nf < 4; ++nf)
                bk[nf] = *(const bf16x8*)(CKt + (cb * FF + f0 + nf * 16 + lid) * TC + kt * 32 + grp * 8);
#pragma unroll
            for (int md = 0; md < 2; ++md)
#pragma unroll
                for (int nf = 0; nf < 4; ++nf)
                    acc[md][nf] = __builtin_amdgcn_mfma_f32_16x16x32_bf16(av[md], bk[nf], acc[md][nf], 0, 0, 0);
        }
#pragma unroll
        for (int md = 0; md < 2; ++md)
#pragma unroll
            for (int nf = 0; nf < 4; ++nf)
#pragma unroll
                for (int r = 0; r < 4; ++r) {
                    const int d = d0 + md * 16 + grp * 4 + r;
                    const int f = f0 + nf * 16 + lid;
                    Stp[(cb * DD + d) * FF + f] = f2bf(acc[md][nf][r]);
                }
    }
    grid.sync();

    // ---------------- P4: exclusive prefix over chunks (grid-stride) ----------------
    for (int gid = blockIdx.x * 256 + tid; gid < NB * DD * FF; gid += nb * 256) {
        const int df = gid & 65535;
        const int b = gid >> 16;
        float run = 0.f;
#pragma unroll
        for (int c = 0; c < NC; ++c) {
            const size_t idx = ((size_t)(b * NC + c) << 16) + df;
            Stb[idx] = f2bf(run);
            run += bf2f(Stp[idx]);
        }
    }
    grid.sync();

    // ---------------- P5: passC — r = tril(CQ CK^T) V + CQ S_prefix (4 waves/tile) ----------------
    for (int t = blockIdx.x; t < 256; t += nb) {
        const int dh = t & 3, c = (t >> 2) & 31, b = t >> 7;
        const size_t rowbase = (size_t)b * LQ + c * 64;
        const size_t cb = (size_t)(b * NC + c);
        unsigned short (*P)[72] = (unsigned short(*)[72])smem;
        __syncthreads();   // protect P reuse across tiles
        f32x4 qk[4];
#pragma unroll
        for (int nt = 0; nt < 4; ++nt) qk[nt] = (f32x4)0.f;
#pragma unroll
        for (int kf = 0; kf < 4; ++kf) {
            bf16x8 aq = *(const bf16x8*)(CQb + (rowbase + w * 16 + lid) * FF + kf * 32 + grp * 8);
            bf16x8 bk[4];
#pragma unroll
            for (int nt = 0; nt < 4; ++nt)
                bk[nt] = *(const bf16x8*)(CKb + (rowbase + nt * 16 + lid) * FF + kf * 32 + grp * 8);
#pragma unroll
            for (int nt = 0; nt < 4; ++nt)
                qk[nt] = __builtin_amdgcn_mfma_f32_16x16x32_bf16(aq, bk[nt], qk[nt], 0, 0, 0);
        }
#pragma unroll
        for (int nt = 0; nt < 4; ++nt)
#pragma unroll
            for (int r = 0; r < 4; ++r) {
                const int row = w * 16 + grp * 4 + r;
                const int col = nt * 16 + lid;
                P[row][col] = f2bf(col <= row ? qk[nt][r] : 0.f);
            }
        __syncthreads();
        const int d0 = dh * 128 + w * 32;
        f32x4 racc[4][2];
#pragma unroll
        for (int ml = 0; ml < 4; ++ml)
#pragma unroll
            for (int nd = 0; nd < 2; ++nd) racc[ml][nd] = (f32x4)0.f;
#pragma unroll
        for (int kt = 0; kt < 2; ++kt) {
            bf16x8 ap[4], bv[2];
#pragma unroll
            for (int ml = 0; ml < 4; ++ml)
                ap[ml] = *(const bf16x8*)&P[ml * 16 + lid][kt * 32 + grp * 8];
#pragma unroll
            for (int nd = 0; nd < 2; ++nd)
                bv[nd] = *(const bf16x8*)(Vt + (cb * DD + d0 + nd * 16 + lid) * TC + kt * 32 + grp * 8);
#pragma unroll
            for (int ml = 0; ml < 4; ++ml)
#pragma unroll
                for (int nd = 0; nd < 2; ++nd)
                    racc[ml][nd] = __builtin_amdgcn_mfma_f32_16x16x32_bf16(ap[ml], bv[nd], racc[ml][nd], 0, 0, 0);
        }
#pragma unroll
        for (int kf = 0; kf < 4; ++kf) {
            bf16x8 aq[4], bs[2];
#pragma unroll
            for (int ml = 0; ml < 4; ++ml)
                aq[ml] = *(const bf16x8*)(CQb + (rowbase + ml * 16 + lid) * FF + kf * 32 + grp * 8);
#pragma unroll
            for (int nd = 0; nd < 2; ++nd)
                bs[nd] = *(const bf16x8*)(Stb + (cb * DD + d0 + nd * 16 + lid) * FF + kf * 32 + grp * 8);
#pragma unroll
            for (int ml = 0; ml < 4; ++ml)
#pragma unroll
                for (int nd = 0; nd < 2; ++nd)
                    racc[ml][nd] = __builtin_amdgcn_mfma_f32_16x16x32_bf16(aq[ml], bs[nd], racc[ml][nd], 0, 0, 0);
        }
#pragma unroll
        for (int ml = 0; ml < 4; ++ml)
#pragma unroll
            for (int nd = 0; nd < 2; ++nd)
#pragma unroll
                for (int r = 0; r < 4; ++r) {
                    const int l = ml * 16 + grp * 4 + r;
                    const int d = d0 + nd * 16 + lid;
                    Rb[(rowbase + l) * DD + d] = racc[ml][nd][r];
                }
    }
    grid.sync();

    // ---------------- P6: position norm + LayerNorm (bf16 out) ----------------
    for (int row = blockIdx.x; row < (int)MR; row += nb) {
        float* sred = (float*)smem;   // rs[4] | rq[4]
        __syncthreads();              // protect sred reuse across rows
        const int l = row & (LQ - 1);
        const float pscale = rsqrtf((float)((l + 1) * PPL));
        float y0 = Rb[(size_t)row * DD + tid] * pscale;
        float y1 = Rb[(size_t)row * DD + 256 + tid] * pscale;
        float s = y0 + y1;
        float q = y0 * y0 + y1 * y1;
#pragma unroll
        for (int off = 32; off >= 1; off >>= 1) {
            s += __shfl_xor(s, off, 64);
            q += __shfl_xor(q, off, 64);
        }
        const int wid = tid >> 6;
        if (lane == 0) { sred[wid] = s; sred[4 + wid] = q; }
        __syncthreads();
        const float ts = sred[0] + sred[1] + sred[2] + sred[3];
        const float tq = sred[4] + sred[5] + sred[6] + sred[7];
        const float mu = ts * (1.0f / DD);
        float var = tq * (1.0f / DD) - mu * mu;
        const float rstd = rsqrtf(var + 1e-5f);
        YNb[(size_t)row * DD + tid] = f2bf((y0 - mu) * rstd * lng[tid] + lnb[tid]);
        YNb[(size_t)row * DD + 256 + tid] = f2bf((y1 - mu) * rstd * lng[tid + 256] + lnb[tid + 256]);
    }
    grid.sync();

    // ---------------- P7: output GEMM (BM=128, BN=64): out = YN@ow + ob + x ----------------
    for (int t = blockIdx.x; t < 256; t += nb) {
        const int cx = t & 7, ry = t >> 3;
        unsigned short* As = smem;
        unsigned short* Bs = smem + 128 * 72;
        const int wr = w >> 1, wc = w & 1;
        const int row0 = ry * 128, col0 = cx * 64;
        f32x4 acc[4][2];
#pragma unroll
        for (int m = 0; m < 4; ++m)
#pragma unroll
            for (int n = 0; n < 2; ++n) acc[m][n] = (f32x4)0.f;
        for (int k0 = 0; k0 < DD; k0 += 64) {
            bf16x8 va[4], vbv[2];
#pragma unroll
            for (int i = 0; i < 4; ++i) {
                const int c = tid + i * 256;
                va[i] = *(const bf16x8*)(YNb + (size_t)(row0 + (c >> 3)) * DD + k0 + (c & 7) * 8);
            }
#pragma unroll
            for (int i = 0; i < 2; ++i) {
                const int c = tid + i * 256;
                vbv[i] = *(const bf16x8*)(owt + (size_t)(col0 + (c >> 3)) * DD + k0 + (c & 7) * 8);
            }
            __syncthreads();
#pragma unroll
            for (int i = 0; i < 4; ++i) {
                const int c = tid + i * 256;
                *(bf16x8*)(As + (c >> 3) * 72 + (c & 7) * 8) = va[i];
            }
#pragma unroll
            for (int i = 0; i < 2; ++i) {
                const int c = tid + i * 256;
                *(bf16x8*)(Bs + (c >> 3) * 72 + (c & 7) * 8) = vbv[i];
            }
            __syncthreads();
#pragma unroll
            for (int kk = 0; kk < 2; ++kk) {
                bf16x8 af[4], bfr[2];
#pragma unroll
                for (int m = 0; m < 4; ++m)
                    af[m] = *(const bf16x8*)(As + (wr * 64 + m * 16 + lid) * 72 + kk * 32 + grp * 8);
#pragma unroll
                for (int n = 0; n < 2; ++n)
                    bfr[n] = *(const bf16x8*)(Bs + (wc * 32 + n * 16 + lid) * 72 + kk * 32 + grp * 8);
#pragma unroll
                for (int m = 0; m < 4; ++m)
#pragma unroll
                    for (int n = 0; n < 2; ++n)
                        acc[m][n] = __builtin_amdgcn_mfma_f32_16x16x32_bf16(af[m], bfr[n], acc[m][n], 0, 0, 0);
            }
        }
#pragma unroll
        for (int m = 0; m < 4; ++m) {
#pragma unroll
            for (int n = 0; n < 2; ++n) {
                const int col = col0 + wc * 32 + n * 16 + lid;
                const float bc = ob[col];
#pragma unroll
                for (int r = 0; r < 4; ++r) {
                    const int row = row0 + wr * 64 + m * 16 + grp * 4 + r;
                    out[(size_t)row * DD + col] = acc[m][n][r] + bc + x[(size_t)row * DD + col];
                }
            }
        }
    }
}

extern "C" void kernel_launch(void* const* d_in, const int* in_sizes, int n_in,
                              void* d_out, int out_size, void* d_ws, size_t ws_size,
                              hipStream_t stream)
{
    const float* x   = (const float*)d_in[0];
    const float* sw  = (const float*)d_in[1];
    const float* kw1 = (const float*)d_in[2];
    const float* kb1 = (const float*)d_in[3];
    const float* kw2 = (const float*)d_in[4];
    const float* kb2 = (const float*)d_in[5];
    const float* qw1 = (const float*)d_in[6];
    const float* qb1 = (const float*)d_in[7];
    const float* qw2 = (const float*)d_in[8];
    const float* qb2 = (const float*)d_in[9];
    const float* vw  = (const float*)d_in[10];
    const float* vb  = (const float*)d_in[11];
    const float* lng = (const float*)d_in[12];
    const float* lnb = (const float*)d_in[13];
    const float* ow  = (const float*)d_in[14];
    const float* ob  = (const float*)d_in[15];
    float* outp = (float*)d_out;
    void* wsv = d_ws;

    // Size the cooperative grid from the runtime's occupancy (deterministic host query).
    int occ = 0;
    hipError_t qe = hipOccupancyMaxActiveBlocksPerMultiprocessor(&occ, mega_kernel, 256, 0);
    if (qe != hipSuccess || occ < 1) occ = 1;
    int grid = occ * NCU;
    if (grid > 512) grid = 512;   // more than 2/CU adds nothing

    void* args[] = {
        (void*)&x, (void*)&sw, (void*)&kw1, (void*)&kb1, (void*)&kw2, (void*)&kb2,
        (void*)&qw1, (void*)&qb1, (void*)&qw2, (void*)&qb2, (void*)&vw, (void*)&vb,
        (void*)&lng, (void*)&lnb, (void*)&ow, (void*)&ob, (void*)&outp, (void*)&wsv
    };
    hipError_t le = hipLaunchCooperativeKernel((const void*)mega_kernel, dim3(grid), dim3(256),
                                               args, 0, stream);
    if (le != hipSuccess && grid != NCU) {
        // last-resort fallback: 1 block/CU is always co-residable
        hipLaunchCooperativeKernel((const void*)mega_kernel, dim3(NCU), dim3(256),
                                   args, 0, stream);
    }
}

// Round 13
// 154.858 us; speedup vs baseline: 2.6505x; 2.6505x over previous
//
#include <hip/hip_runtime.h>
#include <math.h>

// Problem constants
constexpr int NB = 2;        // batch
constexpr int LQ = 2048;     // sequence length
constexpr int DD = 512;      // model dim
constexpr int PPL = 16;      // planes per set
constexpr int TPP = 64;      // total planes (S*P)
constexpr int FF = 128;      // feature dim = 2*TPP (cos,sin interleaved)
constexpr int NC = 32;       // chunks
constexpr int TC = 64;       // chunk length
constexpr float PI_F = 3.14159265358979323846f;

typedef __attribute__((ext_vector_type(4))) float f32x4;
typedef __attribute__((ext_vector_type(8))) short bf16x8;

static __device__ __forceinline__ unsigned short f2bf(float x) {
    union { float f; unsigned u; } v; v.f = x;
    unsigned r = v.u + 0x7fff + ((v.u >> 16) & 1);
    return (unsigned short)(r >> 16);
}
static __device__ __forceinline__ float bf2f(unsigned short u) {
    union { unsigned u; float f; } v; v.u = ((unsigned)u) << 16;
    return v.f;
}

// async global->LDS, 16B per lane; LDS dest = wave-uniform base + lane*16
#define GLOAD16(gp, lp) __builtin_amdgcn_global_load_lds( \
    (const __attribute__((address_space(1))) unsigned int*)(gp), \
    (__attribute__((address_space(3))) unsigned int*)(lp), 16, 0, 0)

// ---------------- prep: cast x->bf16 + all weight transposes, one launch ----------------
__global__ __launch_bounds__(256) void prep_kernel(
    const float* __restrict__ x,
    const float* __restrict__ kw1, const float* __restrict__ qw1,
    const float* __restrict__ vw, const float* __restrict__ ow,
    const float* __restrict__ kw2, const float* __restrict__ qw2,
    unsigned short* __restrict__ xb,
    unsigned short* __restrict__ kw1t, unsigned short* __restrict__ qw1t,
    unsigned short* __restrict__ vwt, unsigned short* __restrict__ owt,
    unsigned short* __restrict__ kw2t, unsigned short* __restrict__ qw2t)
{
    __shared__ float t[32][33];
    const int id = blockIdx.x;
    const int tid = threadIdx.x;
    if (id < 1024) {                       // cast 2M elements
        const int i = id * 2048 + tid * 8;
        float4 a = *(const float4*)(x + i);
        float4 b = *(const float4*)(x + i + 4);
        ushort4 u0 = {f2bf(a.x), f2bf(a.y), f2bf(a.z), f2bf(a.w)};
        ushort4 u1 = {f2bf(b.x), f2bf(b.y), f2bf(b.z), f2bf(b.w)};
        *(ushort4*)(xb + i) = u0;
        *(ushort4*)(xb + i + 4) = u1;
        return;
    }
    const float* W;
    unsigned short* O;
    int K, N, n0, k0;
    if (id < 2048) {                       // 512x512 transposes
        const int rid = id - 1024;
        const int mat = rid >> 8, rem = rid & 255;
        W = (mat == 0) ? kw1 : (mat == 1) ? qw1 : (mat == 2) ? vw : ow;
        O = (mat == 0) ? kw1t : (mat == 1) ? qw1t : (mat == 2) ? vwt : owt;
        K = DD; N = DD;
        n0 = (rem & 15) * 32; k0 = (rem >> 4) * 32;
    } else {                               // 512x64 transposes
        const int rid = id - 2048;
        const int mat = rid >> 5, rem = rid & 31;
        W = mat ? qw2 : kw2;
        O = mat ? qw2t : kw2t;
        K = DD; N = TPP;
        n0 = (rem & 1) * 32; k0 = (rem >> 1) * 32;
    }
    const int tx = tid & 31, ty = tid >> 5;  // 32x8
#pragma unroll
    for (int i = 0; i < 4; ++i)
        t[ty + 8 * i][tx] = W[(size_t)(k0 + ty + 8 * i) * N + n0 + tx];
    __syncthreads();
#pragma unroll
    for (int i = 0; i < 4; ++i)
        O[(size_t)(n0 + ty + 8 * i) * K + k0 + tx] = f2bf(t[tx][ty + 8 * i]);
}

// ---------------- fused x-GEMMs: z=0 -> gelu->hkb, z=1 -> gelu->hqb, z=2 -> Vt ----------------
// BM=128, BN=128, BK=64, 256 thr (4 waves, wave tile 64x64).
// Staging via global_load_lds (16B/lane) into LINEAR [128][64] LDS with XOR slot swizzle:
//   physical 16B-slot p at row r holds logical slot q = p ^ (r&7)   (involution, both sides).
__global__ __launch_bounds__(256) void mgemm_fused(
    const unsigned short* __restrict__ A,
    const unsigned short* __restrict__ kw1t, const unsigned short* __restrict__ qw1t,
    const unsigned short* __restrict__ vwt,
    const float* __restrict__ kb1, const float* __restrict__ qb1, const float* __restrict__ vb,
    unsigned short* __restrict__ hkb, unsigned short* __restrict__ hqb,
    unsigned short* __restrict__ Vt)
{
    const int z = blockIdx.z;
    const unsigned short* Bt = (z == 0) ? kw1t : (z == 1) ? qw1t : vwt;
    const float* bias = (z == 0) ? kb1 : (z == 1) ? qb1 : vb;
    unsigned short* obf = (z == 0) ? hkb : (z == 1) ? hqb : Vt;
    const int K = DD, N = DD;

    __shared__ unsigned short As[128 * 64];
    __shared__ unsigned short Bs[128 * 64];
    const int tid = threadIdx.x;
    const int w = tid >> 6, lane = tid & 63, grp = lane >> 4, lid = lane & 15;
    const int wr = w >> 1, wc = w & 1;   // wave tile: rows wr*64, cols wc*64
    const int row0 = blockIdx.y * 128, col0 = blockIdx.x * 128;
    const int l8 = lane >> 3, s8 = lane & 7;
    const int q = s8 ^ l8;               // logical slot this lane fetches
    f32x4 acc[4][4];
#pragma unroll
    for (int m = 0; m < 4; ++m)
#pragma unroll
        for (int n = 0; n < 4; ++n) acc[m][n] = (f32x4)0.f;

    for (int k0 = 0; k0 < K; k0 += 64) {
        __syncthreads();   // prior MFMA reads done before overwrite
#pragma unroll
        for (int j = 0; j < 4; ++j) {
            const int rbase = w * 32 + j * 8;          // wave-uniform
            const int lrow = rbase + l8;               // per-lane row within tile
            GLOAD16(A  + (size_t)(row0 + lrow) * K + k0 + q * 8, As + rbase * 64);
            GLOAD16(Bt + (size_t)(col0 + lrow) * K + k0 + q * 8, Bs + rbase * 64);
        }
        __syncthreads();   // compiler drains vmcnt(0) before barrier
#pragma unroll
        for (int kk = 0; kk < 2; ++kk) {
            const int xr = lid & 7;
            bf16x8 af[4], bfr[4];
#pragma unroll
            for (int m = 0; m < 4; ++m)
                af[m] = *(const bf16x8*)(As + (wr * 64 + m * 16 + lid) * 64 + (((kk * 4 + grp) ^ xr) * 8));
#pragma unroll
            for (int n = 0; n < 4; ++n)
                bfr[n] = *(const bf16x8*)(Bs + (wc * 64 + n * 16 + lid) * 64 + (((kk * 4 + grp) ^ xr) * 8));
#pragma unroll
            for (int m = 0; m < 4; ++m)
#pragma unroll
                for (int n = 0; n < 4; ++n)
                    acc[m][n] = __builtin_amdgcn_mfma_f32_16x16x32_bf16(af[m], bfr[n], acc[m][n], 0, 0, 0);
        }
    }
#pragma unroll
    for (int m = 0; m < 4; ++m) {
#pragma unroll
        for (int n = 0; n < 4; ++n) {
            const int col = col0 + wc * 64 + n * 16 + lid;
            const float bc = bias[col];
            if (z == 2) {
                const int rowb = row0 + wr * 64 + m * 16 + grp * 4;
                const int b = rowb >> 11, l = rowb & (LQ - 1);
                const int c = l >> 6, t0 = l & 63;
                ushort4 u;
                u.x = f2bf(acc[m][n][0] + bc);
                u.y = f2bf(acc[m][n][1] + bc);
                u.z = f2bf(acc[m][n][2] + bc);
                u.w = f2bf(acc[m][n][3] + bc);
                *(ushort4*)(Vt + ((size_t)((b * NC + c) * DD) + col) * TC + t0) = u;
            } else {
#pragma unroll
                for (int r = 0; r < 4; ++r) {
                    const int row = row0 + wr * 64 + m * 16 + grp * 4 + r;
                    float v = acc[m][n][r] + bc;
                    v = 0.5f * v * (1.0f + erff(v * 0.70710678118654752f));
                    obf[(size_t)row * N + col] = f2bf(v);
                }
            }
        }
    }
}

// ---------------- fused phase GEMM: y=0 -> K features, y=1 -> Q features ----------------
// BM=64, N=64, K=512. 4 waves, wave tile 16 rows x 64 cols.
__global__ __launch_bounds__(256) void phase_fused(
    const unsigned short* __restrict__ hkb, const unsigned short* __restrict__ hqb,
    const unsigned short* __restrict__ kw2t, const unsigned short* __restrict__ qw2t,
    const float* __restrict__ kb2, const float* __restrict__ qb2,
    const float* __restrict__ sw,
    unsigned short* __restrict__ CKb, unsigned short* __restrict__ CQb,
    unsigned short* __restrict__ CKt)
{
    const int isq = blockIdx.y;
    const unsigned short* A = isq ? hqb : hkb;
    const unsigned short* Bt = isq ? qw2t : kw2t;
    const float* b2 = isq ? qb2 : kb2;
    unsigned short* FROW = isq ? CQb : CKb;
    const int K = DD;

    __shared__ unsigned short As[64 * 72];
    __shared__ unsigned short Bs[64 * 72];
    const int tid = threadIdx.x;
    const int w = tid >> 6, lane = tid & 63, grp = lane >> 4, lid = lane & 15;
    const int row0 = blockIdx.x * 64;
    f32x4 acc[4];
#pragma unroll
    for (int n = 0; n < 4; ++n) acc[n] = (f32x4)0.f;

    for (int k0 = 0; k0 < K; k0 += 64) {
        bf16x8 va[2], vbv[2];
#pragma unroll
        for (int i = 0; i < 2; ++i) {
            const int c = tid + i * 256;
            va[i] = *(const bf16x8*)(A + (size_t)(row0 + (c >> 3)) * K + k0 + (c & 7) * 8);
            vbv[i] = *(const bf16x8*)(Bt + (size_t)(c >> 3) * K + k0 + (c & 7) * 8);
        }
        __syncthreads();
#pragma unroll
        for (int i = 0; i < 2; ++i) {
            const int c = tid + i * 256;
            *(bf16x8*)(As + (c >> 3) * 72 + (c & 7) * 8) = va[i];
            *(bf16x8*)(Bs + (c >> 3) * 72 + (c & 7) * 8) = vbv[i];
        }
        __syncthreads();
#pragma unroll
        for (int kk = 0; kk < 2; ++kk) {
            bf16x8 af, bfr[4];
            af = *(const bf16x8*)(As + (w * 16 + lid) * 72 + kk * 32 + grp * 8);
#pragma unroll
            for (int n = 0; n < 4; ++n)
                bfr[n] = *(const bf16x8*)(Bs + (n * 16 + lid) * 72 + kk * 32 + grp * 8);
#pragma unroll
            for (int n = 0; n < 4; ++n)
                acc[n] = __builtin_amdgcn_mfma_f32_16x16x32_bf16(af, bfr[n], acc[n], 0, 0, 0);
        }
    }
    float wsm[4] = {1.f, 1.f, 1.f, 1.f};
    if (isq) {
        float s0 = sw[0], s1 = sw[1], s2 = sw[2], s3 = sw[3];
        float mx = fmaxf(fmaxf(s0, s1), fmaxf(s2, s3));
        float e0 = __expf(s0 - mx), e1 = __expf(s1 - mx), e2 = __expf(s2 - mx), e3 = __expf(s3 - mx);
        float inv = 1.0f / (e0 + e1 + e2 + e3);
        wsm[0] = e0 * inv; wsm[1] = e1 * inv; wsm[2] = e2 * inv; wsm[3] = e3 * inv;
    }
#pragma unroll
    for (int n = 0; n < 4; ++n) {
        const int p = n * 16 + lid;
        const float bc = b2[p];
        const float wg = isq ? wsm[p >> 4] : 1.0f;
#pragma unroll
        for (int r = 0; r < 4; ++r) {
            const int row = row0 + w * 16 + grp * 4 + r;
            float u = acc[n][r] + bc;
            float th = 1.0f - 2.0f / (__expf(2.0f * u) + 1.0f);   // tanh(u)
            float ph = th * PI_F;
            float sp, cp;
            __sincosf(ph, &sp, &cp);
            const unsigned short cb = f2bf(cp * wg), sb = f2bf(sp * wg);
            FROW[(size_t)row * FF + 2 * p + 0] = cb;
            FROW[(size_t)row * FF + 2 * p + 1] = sb;
            if (!isq) {
                const int b = row >> 11, l = row & (LQ - 1);
                const int c = l >> 6, t = l & 63;
                const size_t base = ((size_t)(b * NC + c) * FF) * TC;
                CKt[base + (size_t)(2 * p + 0) * TC + t] = cb;
                CKt[base + (size_t)(2 * p + 1) * TC + t] = sb;
            }
        }
    }
}

// ---------------- pass A: per-chunk state (bf16) Stp[b][c][d][f] = sum_t Vt[d][t]*CKt[f][t] ----------------
__global__ __launch_bounds__(256) void passA_mfma(
    const unsigned short* __restrict__ Vt, const unsigned short* __restrict__ CKt,
    unsigned short* __restrict__ Stp)
{
    const int tid = threadIdx.x;
    const int w = tid >> 6, lane = tid & 63, grp = lane >> 4, lid = lane & 15;
    const int dq = blockIdx.x, c = blockIdx.y, b = blockIdx.z;
    const int d0 = dq * 128 + w * 32;
    const size_t cb = (size_t)(b * NC + c);
    f32x4 acc[2][8];
#pragma unroll
    for (int md = 0; md < 2; ++md)
#pragma unroll
        for (int nf = 0; nf < 8; ++nf) acc[md][nf] = (f32x4)0.f;
#pragma unroll
    for (int kt = 0; kt < 2; ++kt) {
        bf16x8 av[2], bk[8];
#pragma unroll
        for (int md = 0; md < 2; ++md)
            av[md] = *(const bf16x8*)(Vt + (cb * DD + d0 + md * 16 + lid) * TC + kt * 32 + grp * 8);
#pragma unroll
        for (int nf = 0; nf < 8; ++nf)
            bk[nf] = *(const bf16x8*)(CKt + (cb * FF + nf * 16 + lid) * TC + kt * 32 + grp * 8);
#pragma unroll
        for (int md = 0; md < 2; ++md)
#pragma unroll
            for (int nf = 0; nf < 8; ++nf)
                acc[md][nf] = __builtin_amdgcn_mfma_f32_16x16x32_bf16(av[md], bk[nf], acc[md][nf], 0, 0, 0);
    }
#pragma unroll
    for (int md = 0; md < 2; ++md)
#pragma unroll
        for (int nf = 0; nf < 8; ++nf)
#pragma unroll
            for (int r = 0; r < 4; ++r) {
                const int d = d0 + md * 16 + grp * 4 + r;
                const int f = nf * 16 + lid;
                Stp[(cb * DD + d) * FF + f] = f2bf(acc[md][nf][r]);
            }
}

// ---------------- pass B: exclusive prefix over chunks (bf16 in, f32 run, bf16 out) ----------------
__global__ __launch_bounds__(256) void prefix_mfma(
    const unsigned short* __restrict__ Stp, unsigned short* __restrict__ Stb)
{
    const int gid = blockIdx.x * 256 + threadIdx.x;  // b*(DD*FF) + d*FF + f
    const int b = gid >> 16;                          // DD*FF = 65536
    const int df = gid & 65535;
    float run = 0.f;
#pragma unroll
    for (int c = 0; c < NC; ++c) {
        const size_t idx = ((size_t)(b * NC + c) << 16) + df;
        Stb[idx] = f2bf(run);
        run += bf2f(Stp[idx]);
    }
}

// ---------------- pass C: r = tril(CQ CK^T) V + CQ S_prefix (4 waves) ----------------
__global__ __launch_bounds__(256) void passC_mfma(
    const unsigned short* __restrict__ CQb, const unsigned short* __restrict__ CKb,
    const unsigned short* __restrict__ Vt, const unsigned short* __restrict__ Stb,
    float* __restrict__ R)
{
    __shared__ unsigned short P[64][72];
    const int tid = threadIdx.x;
    const int w = tid >> 6, lane = tid & 63, grp = lane >> 4, lid = lane & 15;
    const int dh = blockIdx.x, c = blockIdx.y, b = blockIdx.z;
    const size_t rowbase = (size_t)b * LQ + c * 64;
    const size_t cb = (size_t)(b * NC + c);
    f32x4 qk[4];
#pragma unroll
    for (int nt = 0; nt < 4; ++nt) qk[nt] = (f32x4)0.f;
#pragma unroll
    for (int kf = 0; kf < 4; ++kf) {
        bf16x8 aq = *(const bf16x8*)(CQb + (rowbase + w * 16 + lid) * FF + kf * 32 + grp * 8);
        bf16x8 bk[4];
#pragma unroll
        for (int nt = 0; nt < 4; ++nt)
            bk[nt] = *(const bf16x8*)(CKb + (rowbase + nt * 16 + lid) * FF + kf * 32 + grp * 8);
#pragma unroll
        for (int nt = 0; nt < 4; ++nt)
            qk[nt] = __builtin_amdgcn_mfma_f32_16x16x32_bf16(aq, bk[nt], qk[nt], 0, 0, 0);
    }
#pragma unroll
    for (int nt = 0; nt < 4; ++nt)
#pragma unroll
        for (int r = 0; r < 4; ++r) {
            const int row = w * 16 + grp * 4 + r;
            const int col = nt * 16 + lid;
            P[row][col] = f2bf(col <= row ? qk[nt][r] : 0.f);
        }
    __syncthreads();
    const int d0 = dh * 128 + w * 32;
    f32x4 racc[4][2];
#pragma unroll
    for (int ml = 0; ml < 4; ++ml)
#pragma unroll
        for (int nd = 0; nd < 2; ++nd) racc[ml][nd] = (f32x4)0.f;
#pragma unroll
    for (int kt = 0; kt < 2; ++kt) {
        bf16x8 ap[4], bv[2];
#pragma unroll
        for (int ml = 0; ml < 4; ++ml)
            ap[ml] = *(const bf16x8*)&P[ml * 16 + lid][kt * 32 + grp * 8];
#pragma unroll
        for (int nd = 0; nd < 2; ++nd)
            bv[nd] = *(const bf16x8*)(Vt + (cb * DD + d0 + nd * 16 + lid) * TC + kt * 32 + grp * 8);
#pragma unroll
        for (int ml = 0; ml < 4; ++ml)
#pragma unroll
            for (int nd = 0; nd < 2; ++nd)
                racc[ml][nd] = __builtin_amdgcn_mfma_f32_16x16x32_bf16(ap[ml], bv[nd], racc[ml][nd], 0, 0, 0);
    }
#pragma unroll
    for (int kf = 0; kf < 4; ++kf) {
        bf16x8 aq[4], bs[2];
#pragma unroll
        for (int ml = 0; ml < 4; ++ml)
            aq[ml] = *(const bf16x8*)(CQb + (rowbase + ml * 16 + lid) * FF + kf * 32 + grp * 8);
#pragma unroll
        for (int nd = 0; nd < 2; ++nd)
            bs[nd] = *(const bf16x8*)(Stb + (cb * DD + d0 + nd * 16 + lid) * FF + kf * 32 + grp * 8);
#pragma unroll
        for (int ml = 0; ml < 4; ++ml)
#pragma unroll
            for (int nd = 0; nd < 2; ++nd)
                racc[ml][nd] = __builtin_amdgcn_mfma_f32_16x16x32_bf16(aq[ml], bs[nd], racc[ml][nd], 0, 0, 0);
    }
#pragma unroll
    for (int ml = 0; ml < 4; ++ml)
#pragma unroll
        for (int nd = 0; nd < 2; ++nd)
#pragma unroll
            for (int r = 0; r < 4; ++r) {
                const int l = ml * 16 + grp * 4 + r;
                const int d = d0 + nd * 16 + lid;
                R[(rowbase + l) * DD + d] = racc[ml][nd][r];
            }
}

// ---------------- position norm + LayerNorm (bf16 out) ----------------
__global__ __launch_bounds__(256) void ln_kernel(
    const float* __restrict__ R, const float* __restrict__ g,
    const float* __restrict__ be, unsigned short* __restrict__ YN)
{
    const int row = blockIdx.x;
    const int l = row & (LQ - 1);
    const int tid = threadIdx.x;
    const float pscale = rsqrtf((float)((l + 1) * PPL));
    float y0 = R[(size_t)row * DD + tid] * pscale;
    float y1 = R[(size_t)row * DD + 256 + tid] * pscale;
    float s = y0 + y1;
    float q = y0 * y0 + y1 * y1;
#pragma unroll
    for (int off = 32; off >= 1; off >>= 1) {
        s += __shfl_xor(s, off, 64);
        q += __shfl_xor(q, off, 64);
    }
    __shared__ float rs[4], rq[4];
    const int wid = tid >> 6, lane = tid & 63;
    if (lane == 0) { rs[wid] = s; rq[wid] = q; }
    __syncthreads();
    const float ts = rs[0] + rs[1] + rs[2] + rs[3];
    const float tq = rq[0] + rq[1] + rq[2] + rq[3];
    const float mu = ts * (1.0f / DD);
    float var = tq * (1.0f / DD) - mu * mu;
    const float rstd = rsqrtf(var + 1e-5f);
    YN[(size_t)row * DD + tid] = f2bf((y0 - mu) * rstd * g[tid] + be[tid]);
    YN[(size_t)row * DD + 256 + tid] = f2bf((y1 - mu) * rstd * g[tid + 256] + be[tid + 256]);
}

// ---------------- output GEMM: BM=128, BN=64, out = acc + bias + resid ----------------
__global__ __launch_bounds__(256) void mgemm_out(
    const unsigned short* __restrict__ A, const unsigned short* __restrict__ Bt,
    const float* __restrict__ bias, const float* __restrict__ resid,
    float* __restrict__ out)
{
    const int K = DD, N = DD;
    __shared__ unsigned short As[128 * 72];
    __shared__ unsigned short Bs[64 * 72];
    const int tid = threadIdx.x;
    const int w = tid >> 6, lane = tid & 63, grp = lane >> 4, lid = lane & 15;
    const int wr = w >> 1, wc = w & 1;   // wave tile: rows wr*64, cols wc*32
    const int row0 = blockIdx.y * 128, col0 = blockIdx.x * 64;
    f32x4 acc[4][2];
#pragma unroll
    for (int m = 0; m < 4; ++m)
#pragma unroll
        for (int n = 0; n < 2; ++n) acc[m][n] = (f32x4)0.f;

    for (int k0 = 0; k0 < K; k0 += 64) {
        bf16x8 va[4], vbv[2];
#pragma unroll
        for (int i = 0; i < 4; ++i) {
            const int c = tid + i * 256;
            va[i] = *(const bf16x8*)(A + (size_t)(row0 + (c >> 3)) * K + k0 + (c & 7) * 8);
        }
#pragma unroll
        for (int i = 0; i < 2; ++i) {
            const int c = tid + i * 256;
            vbv[i] = *(const bf16x8*)(Bt + (size_t)(col0 + (c >> 3)) * K + k0 + (c & 7) * 8);
        }
        __syncthreads();
#pragma unroll
        for (int i = 0; i < 4; ++i) {
            const int c = tid + i * 256;
            *(bf16x8*)(As + (c >> 3) * 72 + (c & 7) * 8) = va[i];
        }
#pragma unroll
        for (int i = 0; i < 2; ++i) {
            const int c = tid + i * 256;
            *(bf16x8*)(Bs + (c >> 3) * 72 + (c & 7) * 8) = vbv[i];
        }
        __syncthreads();
#pragma unroll
        for (int kk = 0; kk < 2; ++kk) {
            bf16x8 af[4], bfr[2];
#pragma unroll
            for (int m = 0; m < 4; ++m)
                af[m] = *(const bf16x8*)(As + (wr * 64 + m * 16 + lid) * 72 + kk * 32 + grp * 8);
#pragma unroll
            for (int n = 0; n < 2; ++n)
                bfr[n] = *(const bf16x8*)(Bs + (wc * 32 + n * 16 + lid) * 72 + kk * 32 + grp * 8);
#pragma unroll
            for (int m = 0; m < 4; ++m)
#pragma unroll
                for (int n = 0; n < 2; ++n)
                    acc[m][n] = __builtin_amdgcn_mfma_f32_16x16x32_bf16(af[m], bfr[n], acc[m][n], 0, 0, 0);
        }
    }
#pragma unroll
    for (int m = 0; m < 4; ++m) {
#pragma unroll
        for (int n = 0; n < 2; ++n) {
            const int col = col0 + wc * 32 + n * 16 + lid;
            const float bc = bias[col];
#pragma unroll
            for (int r = 0; r < 4; ++r) {
                const int row = row0 + wr * 64 + m * 16 + grp * 4 + r;
                out[(size_t)row * N + col] = acc[m][n][r] + bc + resid[(size_t)row * N + col];
            }
        }
    }
}

extern "C" void kernel_launch(void* const* d_in, const int* in_sizes, int n_in,
                              void* d_out, int out_size, void* d_ws, size_t ws_size,
                              hipStream_t stream)
{
    const float* x   = (const float*)d_in[0];
    const float* sw  = (const float*)d_in[1];
    const float* kw1 = (const float*)d_in[2];
    const float* kb1 = (const float*)d_in[3];
    const float* kw2 = (const float*)d_in[4];
    const float* kb2 = (const float*)d_in[5];
    const float* qw1 = (const float*)d_in[6];
    const float* qb1 = (const float*)d_in[7];
    const float* qw2 = (const float*)d_in[8];
    const float* qb2 = (const float*)d_in[9];
    const float* vw  = (const float*)d_in[10];
    const float* vb  = (const float*)d_in[11];
    const float* lng = (const float*)d_in[12];
    const float* lnb = (const float*)d_in[13];
    const float* ow  = (const float*)d_in[14];
    const float* ob  = (const float*)d_in[15];
    float* out = (float*)d_out;

    const size_t MR = (size_t)NB * LQ;  // 4096 rows
    float* ws = (float*)d_ws;
    float* Rb = ws;                                   // 2M f32
    unsigned short* xb   = (unsigned short*)(Rb + MR * DD);
    unsigned short* hkb  = xb + MR * DD;
    unsigned short* hqb  = hkb + MR * DD;
    unsigned short* YNb  = hqb + MR * DD;
    unsigned short* Vt   = YNb + MR * DD;
    unsigned short* CQb  = Vt + MR * DD;
    unsigned short* CKb  = CQb + MR * FF;
    unsigned short* CKt  = CKb + MR * FF;
    unsigned short* Stp  = CKt + MR * FF;             // 4M shorts
    unsigned short* Stb  = Stp + (size_t)NB * NC * DD * FF;  // 4M shorts
    unsigned short* kw1t = Stb + (size_t)NB * NC * DD * FF;
    unsigned short* qw1t = kw1t + (size_t)DD * DD;
    unsigned short* vwt  = qw1t + (size_t)DD * DD;
    unsigned short* owt  = vwt + (size_t)DD * DD;
    unsigned short* kw2t = owt + (size_t)DD * DD;
    unsigned short* qw2t = kw2t + (size_t)TPP * DD;

    const dim3 blk(256);
    hipLaunchKernelGGL(prep_kernel, dim3(2112), blk, 0, stream,
                       x, kw1, qw1, vw, ow, kw2, qw2,
                       xb, kw1t, qw1t, vwt, owt, kw2t, qw2t);
    hipLaunchKernelGGL(mgemm_fused, dim3(DD / 128, MR / 128, 3), blk, 0, stream,
                       xb, kw1t, qw1t, vwt, kb1, qb1, vb, hkb, hqb, Vt);
    hipLaunchKernelGGL(phase_fused, dim3(MR / 64, 2), blk, 0, stream,
                       hkb, hqb, kw2t, qw2t, kb2, qb2, sw, CKb, CQb, CKt);
    hipLaunchKernelGGL(passA_mfma, dim3(4, NC, NB), blk, 0, stream, Vt, CKt, Stp);
    hipLaunchKernelGGL(prefix_mfma, dim3((NB * DD * FF) / 256), blk, 0, stream, Stp, Stb);
    hipLaunchKernelGGL(passC_mfma, dim3(4, NC, NB), blk, 0, stream, CQb, CKb, Vt, Stb, Rb);
    hipLaunchKernelGGL(ln_kernel, dim3((unsigned)MR), blk, 0, stream, Rb, lng, lnb, YNb);
    hipLaunchKernelGGL(mgemm_out, dim3(DD / 64, MR / 128), blk, 0, stream, YNb, owt, ob, x, out);
}